// Round 1
// baseline (190.232 us; speedup 1.0000x reference)
//
#include <hip/hip_runtime.h>
#include <math.h>

#define NROWS 32768
#define NCODE 1024
#define AMB_CAP 8192
#define GAP_THRESH 1.5e-4f  // exact fp32 gap; emulation err ~1e-5, np-ref rounding ~2e-5

typedef __attribute__((ext_vector_type(8))) short bf16x8;   // 8 bf16 = 4 VGPRs
typedef __attribute__((ext_vector_type(4))) float f32x4;    // MFMA acc

__device__ __forceinline__ unsigned short bf16_rne(float f) {
    unsigned u = __float_as_uint(f);
    unsigned r = u + 0x7FFFu + ((u >> 16) & 1u);
    return (unsigned short)(r >> 16);
}

// ---------------------------------------------------------------------------
// prep: cn4 = ||c||^2+4, minK=+inf bits, zero counter/gsumsq/ticket,
// codebook -> frag-major split-bf16 of (-2c) (wsB). 16 blocks x 64 codes.
// r14: B pre-scaled by -2 so vq_main's MFMA chain computes cn4 - 2*x.c
// directly with the accumulator initialized to cn4 (C/D col = code).
// ---------------------------------------------------------------------------
__global__ __launch_bounds__(64) void vq_prep(
    const float* __restrict__ cb, float* __restrict__ cn4,
    unsigned* __restrict__ minK, unsigned* __restrict__ counter,
    float* __restrict__ gsumsq, unsigned* __restrict__ ticket,
    unsigned short* __restrict__ wsB)
{
    int c = blockIdx.x * 64 + threadIdx.x;
    if (c == 0) { *counter = 0u; *gsumsq = 0.f; *ticket = 0u; }
    float v[64];
    const float4* src = (const float4*)(cb + (size_t)c * 64);
    float s = 0.f;
    #pragma unroll
    for (int i = 0; i < 16; i++) {
        float4 t = src[i];
        v[i*4+0] = t.x; v[i*4+1] = t.y; v[i*4+2] = t.z; v[i*4+3] = t.w;
        s += t.x*t.x + t.y*t.y + t.z*t.z + t.w*t.w;
    }
    cn4[c] = s + 4.0f;
    minK[c] = 0x7F800000u;   // +inf bits (full dists >= 0 -> raw-bit order ok)
    int cc = c >> 6, ct = (c >> 4) & 3, cl = c & 15;
    #pragma unroll
    for (int q = 0; q < 4; q++) {
        int half = q & 1, lo = q >> 1;
        #pragma unroll
        for (int g = 0; g < 4; g++) {
            unsigned short u8[8] __attribute__((aligned(16)));
            #pragma unroll
            for (int j = 0; j < 8; j++) {
                float f = -2.0f * v[half*32 + g*8 + j];   // exact scale (exp shift)
                unsigned short h = bf16_rne(f);
                if (lo) h = bf16_rne(f - __uint_as_float((unsigned)h << 16));
                u8[j] = h;
            }
            size_t off = (size_t)cc * 8192 + ct * 2048 + q * 512 + (g * 16 + cl) * 8;
            *(uint4*)(wsB + off) = *(const uint4*)u8;
        }
    }
}

// ---------------------------------------------------------------------------
// main (r14): NO LDS staging of B. wsB is 256 KB == L2-resident on every XCD
// (guide lesson #7: staging L2-fitting data is pure overhead). Each wave owns
// 32 rows x 256 codes: A split-bf16 frags for two 16-row sets live in regs,
// B frags are read per-lane straight from L2 (coalesced 16 B/lane, tile
// stride 4096 B), so the K-loop has ZERO barriers -- waves run free and the
// compiler vmcnt-pipelines the 4 loads/tile under the 12-MFMA chain.
// Acc is initialized to cn4 (per-column) and B is pre-scaled by -2, so
// wv = acc[r] with no per-dist fmaf/add. 512 blocks x 512 thr, 64 rows/blk.
// ---------------------------------------------------------------------------
__global__ __launch_bounds__(512, 4) void vq_main(
    const float* __restrict__ x, const float* __restrict__ cb,
    const unsigned short* __restrict__ wsB, const float* __restrict__ cn4,
    float* __restrict__ out, unsigned* __restrict__ minK,
    unsigned* __restrict__ counter, int* __restrict__ amb,
    float* __restrict__ gsumsq)
{
    __shared__ float    cn4L[1024];
    __shared__ unsigned scrE[1024];        // per-block per-code min full dist (raw bits)
    __shared__ float mD1[256], mD2[256];   // [row 0..63][quarter 0..3]
    __shared__ int   mI1[256];
    __shared__ int   tokS[64];
    __shared__ float redS[8];

    const int tid = threadIdx.x;
    const int lane = tid & 63;
    const int wi = tid >> 6;         // 0..7
    const int rh = wi >> 2;          // row half: rows rh*32 .. rh*32+31
    const int h2 = wi & 3;           // code quarter: codes h2*256 .. +255
    const int ln15 = lane & 15;
    const int q = lane >> 4;
    const int row0 = blockIdx.x * 64;

    // stage cn4 (1024 f32) + init scrE
    cn4L[tid]       = cn4[tid];
    cn4L[512 + tid] = cn4[512 + tid];
    scrE[tid]       = 0x7F800000u;
    scrE[512 + tid] = 0x7F800000u;

    // ---- A: two 16-row sets fp32 -> split-bf16 frags in regs; norms via shfl ----
    bf16x8 AH0[2], AH1[2], AL0[2], AL1[2];
    float xnm[8];                    // xn(row)-4 for acc rows: [r]=set0, [4+r]=set1
    #pragma unroll
    for (int s = 0; s < 2; s++) {
        const float* xr = x + (size_t)(row0 + rh*32 + s*16 + ln15) * 64 + q * 8;
        float4 f0 = *(const float4*)xr;
        float4 f1 = *(const float4*)(xr + 4);
        float4 f2 = *(const float4*)(xr + 32);
        float4 f3 = *(const float4*)(xr + 36);
        float fa[8] = {f0.x,f0.y,f0.z,f0.w,f1.x,f1.y,f1.z,f1.w};
        float fb[8] = {f2.x,f2.y,f2.z,f2.w,f3.x,f3.y,f3.z,f3.w};
        unsigned short hh8[8] __attribute__((aligned(16)));
        unsigned short ll8[8] __attribute__((aligned(16)));
        unsigned short h28[8] __attribute__((aligned(16)));
        unsigned short l28[8] __attribute__((aligned(16)));
        float ss = 0.f;
        #pragma unroll
        for (int j = 0; j < 8; j++) {
            ss += fa[j]*fa[j] + fb[j]*fb[j];
            unsigned short hh = bf16_rne(fa[j]);
            hh8[j] = hh; ll8[j] = bf16_rne(fa[j] - __uint_as_float((unsigned)hh << 16));
            hh = bf16_rne(fb[j]);
            h28[j] = hh; l28[j] = bf16_rne(fb[j] - __uint_as_float((unsigned)hh << 16));
        }
        AH0[s] = *(const bf16x8*)hh8; AL0[s] = *(const bf16x8*)ll8;
        AH1[s] = *(const bf16x8*)h28; AL1[s] = *(const bf16x8*)l28;
        ss += __shfl_xor(ss, 16);
        ss += __shfl_xor(ss, 32);               // ||x_row(set s, ln15)||^2
        #pragma unroll
        for (int r = 0; r < 4; r++)
            xnm[s*4 + r] = __shfl(ss, (q << 2) | r, 64) - 4.0f;
    }
    __syncthreads();   // cn4L + scrE ready; only barrier before the epilogue

    float d1[8], d2[8];
    int   i1[8];
    #pragma unroll
    for (int r = 0; r < 8; r++) { d1[r] = INFINITY; d2[r] = INFINITY; i1[r] = 0; }

    // ---- tile loop: 16 tiles of 16 codes, B straight from L2, no barriers ----
    const char* wsQ = (const char*)wsB + (size_t)h2 * 65536 + lane * 16;
    #pragma unroll
    for (int t = 0; t < 16; t++) {
        const char* tb = wsQ + t * 4096;
        bf16x8 Bh0 = *(const bf16x8*)(tb);
        bf16x8 Bh1 = *(const bf16x8*)(tb + 1024);
        bf16x8 Bl0 = *(const bf16x8*)(tb + 2048);
        bf16x8 Bl1 = *(const bf16x8*)(tb + 3072);
        const int kid = h2*256 + t*16 + ln15;
        const float cn4v = cn4L[kid];           // per-column (code) bias, shared by all r
        f32x4 a0 = {cn4v, cn4v, cn4v, cn4v};
        f32x4 a1 = a0;
        // 6-product split emulation (hi.hi + hi.lo + lo.hi), B pre-scaled by -2:
        // acc = cn4 - 2*x.c  (== old wv = fmaf(sdot,-2,cn4v))
        a0 = __builtin_amdgcn_mfma_f32_16x16x32_bf16(AH0[0], Bh0, a0, 0, 0, 0);
        a1 = __builtin_amdgcn_mfma_f32_16x16x32_bf16(AH0[1], Bh0, a1, 0, 0, 0);
        a0 = __builtin_amdgcn_mfma_f32_16x16x32_bf16(AH1[0], Bh1, a0, 0, 0, 0);
        a1 = __builtin_amdgcn_mfma_f32_16x16x32_bf16(AH1[1], Bh1, a1, 0, 0, 0);
        a0 = __builtin_amdgcn_mfma_f32_16x16x32_bf16(AH0[0], Bl0, a0, 0, 0, 0);
        a1 = __builtin_amdgcn_mfma_f32_16x16x32_bf16(AH0[1], Bl0, a1, 0, 0, 0);
        a0 = __builtin_amdgcn_mfma_f32_16x16x32_bf16(AH1[0], Bl1, a0, 0, 0, 0);
        a1 = __builtin_amdgcn_mfma_f32_16x16x32_bf16(AH1[1], Bl1, a1, 0, 0, 0);
        a0 = __builtin_amdgcn_mfma_f32_16x16x32_bf16(AL0[0], Bh0, a0, 0, 0, 0);
        a1 = __builtin_amdgcn_mfma_f32_16x16x32_bf16(AL0[1], Bh0, a1, 0, 0, 0);
        a0 = __builtin_amdgcn_mfma_f32_16x16x32_bf16(AL1[0], Bh1, a0, 0, 0, 0);
        a1 = __builtin_amdgcn_mfma_f32_16x16x32_bf16(AL1[1], Bh1, a1, 0, 0, 0);
        float cm = INFINITY;
        #pragma unroll
        for (int r = 0; r < 4; r++) {
            float wv = a0[r];                   // set0 row q*4+r
            bool lt = wv < d1[r];
            d2[r] = lt ? d1[r] : fminf(d2[r], wv);
            i1[r] = lt ? kid   : i1[r];
            d1[r] = lt ? wv    : d1[r];
            cm = fminf(cm, wv + xnm[r]);        // full dist (entropy)
            float wu = a1[r];                   // set1 row 16+q*4+r
            bool lu = wu < d1[4+r];
            d2[4+r] = lu ? d1[4+r] : fminf(d2[4+r], wu);
            i1[4+r] = lu ? kid     : i1[4+r];
            d1[4+r] = lu ? wu      : d1[4+r];
            cm = fminf(cm, wu + xnm[4+r]);
        }
        cm = fminf(cm, __shfl_xor(cm, 16));
        cm = fminf(cm, __shfl_xor(cm, 32));     // min over the wave's 32 rows
        if (q == (t & 3)) atomicMin(&scrE[kid], __float_as_uint(cm));
    }

    // ---- butterfly exact top-2 merge across the 16 code-column lanes ----
    #pragma unroll
    for (int d = 1; d < 16; d <<= 1) {
        #pragma unroll
        for (int r = 0; r < 8; r++) {
            float od1 = __shfl_xor(d1[r], d);
            int   oi1 = __shfl_xor(i1[r], d);
            float od2 = __shfl_xor(d2[r], d);
            bool take = (od1 < d1[r]) || (od1 == d1[r] && oi1 < i1[r]);
            float loser = take ? d1[r] : od1;
            d2[r] = fminf(fminf(d2[r], od2), loser);
            d1[r] = take ? od1 : d1[r];
            i1[r] = take ? oi1 : i1[r];
        }
    }
    if (ln15 == 0) {
        #pragma unroll
        for (int r = 0; r < 4; r++) {
            int rowA = rh*32 + q*4 + r;          // set0
            mD1[rowA*4 + h2] = d1[r];   mI1[rowA*4 + h2] = i1[r];   mD2[rowA*4 + h2] = d2[r];
            int rowB = rowA + 16;                // set1
            mD1[rowB*4 + h2] = d1[4+r]; mI1[rowB*4 + h2] = i1[4+r]; mD2[rowB*4 + h2] = d2[4+r];
        }
    }
    __syncthreads();   // candidates staged; all scrE atomics done

    // ---- exact cross-quarter merge -> token + ambiguity (1 thread/row) ----
    if (tid < 64) {
        float D1 = mD1[tid*4]; int I1 = mI1[tid*4]; float D2 = mD2[tid*4];
        #pragma unroll
        for (int j = 1; j < 4; j++) {
            float b1 = mD1[tid*4 + j];
            int   bi = mI1[tid*4 + j];
            float b2 = mD2[tid*4 + j];
            bool ta = (D1 < b1) || (D1 == b1 && I1 < bi);
            float loser = ta ? b1 : D1;
            D2 = fminf(fminf(D2, b2), loser);
            if (!ta) { D1 = b1; I1 = bi; }
        }
        tokS[tid] = I1;
        if (D2 - D1 < GAP_THRESH) {
            unsigned idx = atomicAdd(counter, 1u);
            if (idx < AMB_CAP) { amb[2*idx] = row0 + tid; amb[2*idx+1] = I1; }
        }
    }

    // ---- entropy: filtered global atomicMin ----
    {
        unsigned u0 = scrE[tid];
        if (u0 < minK[tid]) atomicMin(&minK[tid], u0);          // race benign: monotone
        unsigned u1 = scrE[512 + tid];
        if (u1 < minK[512 + tid]) atomicMin(&minK[512 + tid], u1);
    }
    __syncthreads();   // tokS ready

    // ---- emb gather + sumsq (512 threads x 2 float4 = 64 rows x 16) ----
    {
        float acc2 = 0.f;
        #pragma unroll
        for (int uu = 0; uu < 2; uu++) {
            int u = uu*512 + tid;
            int row = u >> 4, c4 = u & 15;
            int tok = tokS[row];
            float4 c = ((const float4*)(cb + (size_t)tok*64))[c4];
            float4 xx = ((const float4*)(x + (size_t)(row0 + row)*64))[c4];
            ((float4*)(out + (size_t)(row0 + row)*64))[c4] = c;
            float dx = c.x-xx.x, dy = c.y-xx.y, dz = c.z-xx.z, dw = c.w-xx.w;
            acc2 += dx*dx + dy*dy + dz*dz + dw*dw;
        }
        #pragma unroll
        for (int o = 32; o > 0; o >>= 1) acc2 += __shfl_down(acc2, o);
        if (lane == 0) redS[wi] = acc2;
        __syncthreads();
        if (tid == 0) {
            float t = 0.f;
            #pragma unroll
            for (int w = 0; w < 8; w++) t += redS[w];
            atomicAdd(gsumsq, t);
        }
    }
}

// ---------------------------------------------------------------------------
// tail: 64 blocks. (A) fp64 fixup with cb staged through LDS in 4 coalesced
// 64-KB batches. (B) last-ticket block: sum minK + loss. (unchanged)
// ---------------------------------------------------------------------------
__global__ __launch_bounds__(256) void vq_tail(
    const float* __restrict__ x, const float* __restrict__ cb,
    float* __restrict__ out, const unsigned* __restrict__ counter,
    const int* __restrict__ amb, float* __restrict__ gsumsq,
    unsigned* __restrict__ ticket, const unsigned* __restrict__ minK,
    float* __restrict__ out_loss)
{
    __shared__ __align__(16) float cbS[16384];   // 64 KB: 256 codes x 64 dims
    __shared__ double xs[64];
    __shared__ double bd[256];
    __shared__ int    bi[256];
    __shared__ unsigned lastS;
    __shared__ float redS[4];

    const int tid = threadIdx.x;

    // ---- A: fp64 re-decision for ambiguous rows (coalesced cb staging) ----
    unsigned cnt = *counter; if (cnt > AMB_CAP) cnt = AMB_CAP;
    for (unsigned i = blockIdx.x; i < cnt; i += gridDim.x) {
        int row = amb[2*i], oldk = amb[2*i+1];
        __syncthreads();
        if (tid < 64) xs[tid] = (double)x[(size_t)row*64 + tid];
        __syncthreads();
        double xn = 0.0;
        #pragma unroll 8
        for (int d = 0; d < 64; d++) xn += xs[d]*xs[d];
        double best = INFINITY; int bk = 1 << 30;
        for (int b = 0; b < 4; b++) {           // 256 codes per batch
            __syncthreads();                    // cbS free for reuse
            #pragma unroll
            for (int k = 0; k < 16; k++)        // 64 KB coalesced: 16 float4/thread
                ((float4*)cbS)[k*256 + tid] = ((const float4*)cb)[b*4096 + k*256 + tid];
            __syncthreads();
            int kcode = b*256 + tid;
            const int t6 = tid & 63;
            double dot = 0.0, cn2 = 0.0;
            #pragma unroll 8
            for (int dd = 0; dd < 64; dd++) {
                int d = (dd + t6) & 63;         // rotation: 2 lanes/bank (free)
                double cv = (double)cbS[tid*64 + d];
                dot = fma(xs[d], cv, dot);
                cn2 = fma(cv, cv, cn2);
            }
            double dist = (xn - 2.0*dot) + cn2;
            if (dist < best || (dist == best && kcode < bk)) { best = dist; bk = kcode; }
        }
        bd[tid] = best; bi[tid] = bk;
        __syncthreads();
        for (int s = 128; s > 0; s >>= 1) {
            if (tid < s) {
                double od = bd[tid+s]; int ok = bi[tid+s];
                if (od < bd[tid] || (od == bd[tid] && ok < bi[tid])) { bd[tid] = od; bi[tid] = ok; }
            }
            __syncthreads();
        }
        int bestk = bi[0];
        if (bestk != oldk) {
            double part = 0.0;
            if (tid < 64) {
                float cn = cb[(size_t)bestk*64 + tid];
                float co = cb[(size_t)oldk*64 + tid];
                out[(size_t)row*64 + tid] = cn;
                double dn = (double)cn - xs[tid];
                double dl = (double)co - xs[tid];
                part = dn*dn - dl*dl;
            }
            __syncthreads();
            bd[tid] = part;
            __syncthreads();
            for (int s = 128; s > 0; s >>= 1) {
                if (tid < s) bd[tid] += bd[tid+s];
                __syncthreads();
            }
            if (tid == 0) atomicAdd(gsumsq, (float)bd[0]);
        }
    }

    // ---- B: last block assembles the loss ----
    __syncthreads();
    if (tid == 0) {
        __threadfence();
        lastS = (atomicAdd(ticket, 1u) == 63u) ? 1u : 0u;
    }
    __syncthreads();
    if (lastS) {
        __threadfence();
        float s = 0.f;
        #pragma unroll
        for (int jj = 0; jj < 4; jj++)
            s += __uint_as_float(minK[jj*256 + tid]);   // raw bits of positive dists
        #pragma unroll
        for (int o = 32; o > 0; o >>= 1) s += __shfl_down(s, o);
        if ((tid & 63) == 0) redS[tid >> 6] = s;
        __syncthreads();
        if (tid == 0) {
            float gs = atomicAdd(gsumsq, 0.0f);         // coherent device-scope read
            float tot = redS[0] + redS[1] + redS[2] + redS[3];
            out_loss[0] = 1.25f * (gs / 2097152.0f) + 0.1f * (tot / 1024.0f);
        }
    }
}

extern "C" void kernel_launch(void* const* d_in, const int* in_sizes, int n_in,
                              void* d_out, int out_size, void* d_ws, size_t ws_size,
                              hipStream_t stream) {
    const float* x  = (const float*)d_in[0];   // [32768, 64]
    const float* cb = (const float*)d_in[1];   // [1024, 64]
    float* out = (float*)d_out;                // [0,2097152): emb; [2097152]: loss

    char* ws = (char*)d_ws;
    unsigned*       counter = (unsigned*)ws;                    // @0
    float*          gsumsq  = (float*)(ws + 4);                 // @4
    unsigned*       ticket  = (unsigned*)(ws + 8);              // @8
    float*          cn4     = (float*)(ws + 1024);              // 4 KB
    unsigned*       minK    = (unsigned*)(ws + 8192);           // 4 KB
    int*            amb     = (int*)(ws + 16384);               // 64 KB
    unsigned short* wsB     = (unsigned short*)(ws + 131072);   // 256 KB

    vq_prep<<<16,  64,  0, stream>>>(cb, cn4, minK, counter, gsumsq, ticket, wsB);
    vq_main<<<512, 512, 0, stream>>>(x, cb, wsB, cn4, out, minK, counter, amb, gsumsq);
    vq_tail<<<64,  256, 0, stream>>>(x, cb, out, counter, amb, gsumsq, ticket, minK,
                                     out + 2097152);
}

// Round 2
// 112.711 us; speedup vs baseline: 1.6878x; 1.6878x over previous
//
#include <hip/hip_runtime.h>
#include <math.h>

#define NROWS 32768
#define NCODE 1024
#define AMB_CAP 8192
#define GAP_THRESH 1.5e-4f  // exact fp32 gap; emulation err ~1e-5, np-ref rounding ~2e-5

typedef __attribute__((ext_vector_type(8))) short bf16x8;   // 8 bf16 = 4 VGPRs
typedef __attribute__((ext_vector_type(4))) float f32x4;    // MFMA acc

__device__ __forceinline__ unsigned short bf16_rne(float f) {
    unsigned u = __float_as_uint(f);
    unsigned r = u + 0x7FFFu + ((u >> 16) & 1u);
    return (unsigned short)(r >> 16);
}

// ---------------------------------------------------------------------------
// prep: cn4 = ||c||^2+4, minK=+inf bits, zero counter/gsumsq/ticket,
// codebook -> frag-major split-bf16 of (-2c) (wsB). 16 blocks x 64 codes.
// B pre-scaled by -2 (exact exponent shift, commutes with bf16 RNE split) so
// vq_main's MFMA chain computes cn4 - 2*x.c with acc initialized to cn4.
// ---------------------------------------------------------------------------
__global__ __launch_bounds__(64) void vq_prep(
    const float* __restrict__ cb, float* __restrict__ cn4,
    unsigned* __restrict__ minK, unsigned* __restrict__ counter,
    float* __restrict__ gsumsq, unsigned* __restrict__ ticket,
    unsigned short* __restrict__ wsB)
{
    int c = blockIdx.x * 64 + threadIdx.x;
    if (c == 0) { *counter = 0u; *gsumsq = 0.f; *ticket = 0u; }
    float v[64];
    const float4* src = (const float4*)(cb + (size_t)c * 64);
    float s = 0.f;
    #pragma unroll
    for (int i = 0; i < 16; i++) {
        float4 t = src[i];
        v[i*4+0] = t.x; v[i*4+1] = t.y; v[i*4+2] = t.z; v[i*4+3] = t.w;
        s += t.x*t.x + t.y*t.y + t.z*t.z + t.w*t.w;
    }
    cn4[c] = s + 4.0f;
    minK[c] = 0x7F800000u;   // +inf bits (full dists >= 0 -> raw-bit order ok)
    int cc = c >> 6, ct = (c >> 4) & 3, cl = c & 15;
    #pragma unroll
    for (int q = 0; q < 4; q++) {
        int half = q & 1, lo = q >> 1;
        #pragma unroll
        for (int g = 0; g < 4; g++) {
            unsigned short u8[8] __attribute__((aligned(16)));
            #pragma unroll
            for (int j = 0; j < 8; j++) {
                float f = -2.0f * v[half*32 + g*8 + j];   // exact scale
                unsigned short h = bf16_rne(f);
                if (lo) h = bf16_rne(f - __uint_as_float((unsigned)h << 16));
                u8[j] = h;
            }
            size_t off = (size_t)cc * 8192 + ct * 2048 + q * 512 + (g * 16 + cl) * 8;
            *(uint4*)(wsB + off) = *(const uint4*)u8;
        }
    }
}

// ---------------------------------------------------------------------------
// main (r15): zero-barrier K-loop with B read straight from L2 (wsB = 256 KB,
// L2-resident; staging it through LDS was pure barrier overhead -- guide
// lesson #7), but at r13's PROVEN 56-VGPR per-thread footprint. r14's 32-row
// waves doubled live state -> scratch spill -> 420 MB of HBM round-trip
// (WRITE_SIZE 8.5->185 MB was the tell). Here: 8 waves = 4 row-groups x 2
// code-halves; each wave 16 rows x 512 codes = 32 tiles of 16 codes, A frags
// as named scalars, d1/d2/i1[4]. Acc init = cn4[col], B pre-scaled by -2, so
// wv = acc[r] directly (no fmaf/add per dist). 512 blocks x 512 threads.
// ---------------------------------------------------------------------------
__global__ __launch_bounds__(512, 4) void vq_main(
    const float* __restrict__ x, const float* __restrict__ cb,
    const unsigned short* __restrict__ wsB, const float* __restrict__ cn4,
    float* __restrict__ out, unsigned* __restrict__ minK,
    unsigned* __restrict__ counter, int* __restrict__ amb,
    float* __restrict__ gsumsq)
{
    __shared__ float    cn4L[1024];
    __shared__ unsigned scrE[1024];        // per-block per-code min full dist (raw bits)
    __shared__ float mD1[128], mD2[128];   // [row 0..63][half 0..1]
    __shared__ int   mI1[128];
    __shared__ int   tokS[64];
    __shared__ float redS[8];

    const int tid = threadIdx.x;
    const int lane = tid & 63;
    const int wi = tid >> 6;         // 0..7
    const int g = wi >> 1;           // row group 0..3 (16 rows each)
    const int h = wi & 1;            // code half: codes h*512 .. +511
    const int ln15 = lane & 15;
    const int q = lane >> 4;
    const int row0 = blockIdx.x * 64;

    // stage cn4 (1024 f32) + init scrE
    cn4L[tid]       = cn4[tid];
    cn4L[512 + tid] = cn4[512 + tid];
    scrE[tid]       = 0x7F800000u;
    scrE[512 + tid] = 0x7F800000u;

    // ---- A: 16 rows fp32 -> split-bf16 frags in regs; row norms via shfl ----
    bf16x8 Ah0, Ah1, Al0, Al1;
    float xnm4[4];
    {
        const float* xr = x + (size_t)(row0 + g*16 + ln15) * 64 + q * 8;
        float4 f0 = *(const float4*)xr;
        float4 f1 = *(const float4*)(xr + 4);
        float4 f2 = *(const float4*)(xr + 32);
        float4 f3 = *(const float4*)(xr + 36);
        float fa[8] = {f0.x,f0.y,f0.z,f0.w,f1.x,f1.y,f1.z,f1.w};
        float fb[8] = {f2.x,f2.y,f2.z,f2.w,f3.x,f3.y,f3.z,f3.w};
        unsigned short hh8[8] __attribute__((aligned(16)));
        unsigned short ll8[8] __attribute__((aligned(16)));
        unsigned short h28[8] __attribute__((aligned(16)));
        unsigned short l28[8] __attribute__((aligned(16)));
        float ss = 0.f;
        #pragma unroll
        for (int j = 0; j < 8; j++) {
            ss += fa[j]*fa[j] + fb[j]*fb[j];
            unsigned short hh = bf16_rne(fa[j]);
            hh8[j] = hh; ll8[j] = bf16_rne(fa[j] - __uint_as_float((unsigned)hh << 16));
            hh = bf16_rne(fb[j]);
            h28[j] = hh; l28[j] = bf16_rne(fb[j] - __uint_as_float((unsigned)hh << 16));
        }
        Ah0 = *(const bf16x8*)hh8; Al0 = *(const bf16x8*)ll8;
        Ah1 = *(const bf16x8*)h28; Al1 = *(const bf16x8*)l28;
        ss += __shfl_xor(ss, 16);
        ss += __shfl_xor(ss, 32);            // ||x_row(ln15)||^2
        #pragma unroll
        for (int r = 0; r < 4; r++)
            xnm4[r] = __shfl(ss, (q << 2) | r, 64) - 4.0f;  // xn(row q*4+r) - 4
    }
    __syncthreads();   // cn4L + scrE ready; the only barrier before the epilogue

    float d1[4], d2[4];
    int   i1[4];
    #pragma unroll
    for (int r = 0; r < 4; r++) { d1[r] = INFINITY; d2[r] = INFINITY; i1[r] = 0; }

    // ---- tile loop: 32 tiles of 16 codes, B straight from L2, no barriers ----
    // global tile tt = h*32+t -> byte offset tt*4096; frags at +0/1024/2048/3072
    const char* wsQ = (const char*)wsB + (size_t)h * 131072 + lane * 16;
    #pragma unroll 4
    for (int t = 0; t < 32; t++) {
        const char* tb = wsQ + t * 4096;
        bf16x8 Bh0 = *(const bf16x8*)(tb);
        bf16x8 Bh1 = *(const bf16x8*)(tb + 1024);
        bf16x8 Bl0 = *(const bf16x8*)(tb + 2048);
        bf16x8 Bl1 = *(const bf16x8*)(tb + 3072);
        const int kid = h*512 + t*16 + ln15;
        const float cn4v = cn4L[kid];           // per-column (code) bias
        f32x4 a0 = {cn4v, cn4v, cn4v, cn4v};
        // 6-product split emulation (hi.hi + hi.lo + lo.hi), B pre-scaled by -2:
        // acc = cn4 - 2*x.c
        a0 = __builtin_amdgcn_mfma_f32_16x16x32_bf16(Ah0, Bh0, a0, 0, 0, 0);
        a0 = __builtin_amdgcn_mfma_f32_16x16x32_bf16(Ah1, Bh1, a0, 0, 0, 0);
        a0 = __builtin_amdgcn_mfma_f32_16x16x32_bf16(Ah0, Bl0, a0, 0, 0, 0);
        a0 = __builtin_amdgcn_mfma_f32_16x16x32_bf16(Ah1, Bl1, a0, 0, 0, 0);
        a0 = __builtin_amdgcn_mfma_f32_16x16x32_bf16(Al0, Bh0, a0, 0, 0, 0);
        a0 = __builtin_amdgcn_mfma_f32_16x16x32_bf16(Al1, Bh1, a0, 0, 0, 0);
        float cm = INFINITY;
        #pragma unroll
        for (int r = 0; r < 4; r++) {
            float wv = a0[r];                   // row q*4+r, code kid
            bool lt = wv < d1[r];
            d2[r] = lt ? d1[r] : fminf(d2[r], wv);
            i1[r] = lt ? kid   : i1[r];
            d1[r] = lt ? wv    : d1[r];
            cm = fminf(cm, wv + xnm4[r]);       // full dist (entropy)
        }
        cm = fminf(cm, __shfl_xor(cm, 16));
        cm = fminf(cm, __shfl_xor(cm, 32));     // min over wave's 16 rows
        if (q == (t & 3)) atomicMin(&scrE[kid], __float_as_uint(cm));
    }

    // ---- butterfly exact top-2 merge across the 16 code-column lanes ----
    #pragma unroll
    for (int d = 1; d < 16; d <<= 1) {
        #pragma unroll
        for (int r = 0; r < 4; r++) {
            float od1 = __shfl_xor(d1[r], d);
            int   oi1 = __shfl_xor(i1[r], d);
            float od2 = __shfl_xor(d2[r], d);
            bool take = (od1 < d1[r]) || (od1 == d1[r] && oi1 < i1[r]);
            float loser = take ? d1[r] : od1;
            d2[r] = fminf(fminf(d2[r], od2), loser);
            d1[r] = take ? od1 : d1[r];
            i1[r] = take ? oi1 : i1[r];
        }
    }
    if (ln15 == 0) {
        #pragma unroll
        for (int r = 0; r < 4; r++) {
            int idx = (g*16 + q*4 + r) * 2 + h;
            mD1[idx] = d1[r]; mI1[idx] = i1[r]; mD2[idx] = d2[r];
        }
    }
    __syncthreads();   // per-half candidates staged; all scrE atomics done

    // ---- exact cross-half merge -> token + ambiguity (1 thread/row) ----
    if (tid < 64) {
        float a1 = mD1[tid*2],   b1 = mD1[tid*2+1];
        int   ai = mI1[tid*2],   bi = mI1[tid*2+1];
        float a2 = mD2[tid*2],   b2 = mD2[tid*2+1];
        bool ta = (a1 < b1) || (a1 == b1 && ai < bi);
        float D1 = ta ? a1 : b1;
        int   I1 = ta ? ai : bi;
        float D2 = ta ? fminf(a2, b1) : fminf(b2, a1);
        tokS[tid] = I1;
        if (D2 - D1 < GAP_THRESH) {
            unsigned idx = atomicAdd(counter, 1u);
            if (idx < AMB_CAP) { amb[2*idx] = row0 + tid; amb[2*idx+1] = I1; }
        }
    }

    // ---- entropy: filtered global atomicMin ----
    {
        unsigned u0 = scrE[tid];
        if (u0 < minK[tid]) atomicMin(&minK[tid], u0);          // race benign: monotone
        unsigned u1 = scrE[512 + tid];
        if (u1 < minK[512 + tid]) atomicMin(&minK[512 + tid], u1);
    }
    __syncthreads();   // tokS ready

    // ---- emb gather + sumsq (512 threads x 2 float4 = 64 rows x 16) ----
    {
        float acc2 = 0.f;
        #pragma unroll
        for (int uu = 0; uu < 2; uu++) {
            int u = uu*512 + tid;
            int row = u >> 4, c4 = u & 15;
            int tok = tokS[row];
            float4 c = ((const float4*)(cb + (size_t)tok*64))[c4];
            float4 xx = ((const float4*)(x + (size_t)(row0 + row)*64))[c4];
            ((float4*)(out + (size_t)(row0 + row)*64))[c4] = c;
            float dx = c.x-xx.x, dy = c.y-xx.y, dz = c.z-xx.z, dw = c.w-xx.w;
            acc2 += dx*dx + dy*dy + dz*dz + dw*dw;
        }
        #pragma unroll
        for (int o = 32; o > 0; o >>= 1) acc2 += __shfl_down(acc2, o);
        if (lane == 0) redS[wi] = acc2;
        __syncthreads();
        if (tid == 0) {
            float t = 0.f;
            #pragma unroll
            for (int w = 0; w < 8; w++) t += redS[w];
            atomicAdd(gsumsq, t);
        }
    }
}

// ---------------------------------------------------------------------------
// tail: 64 blocks. (A) fp64 fixup with cb staged through LDS in 4 coalesced
// 64-KB batches. (B) last-ticket block: sum minK + loss. (unchanged)
// ---------------------------------------------------------------------------
__global__ __launch_bounds__(256) void vq_tail(
    const float* __restrict__ x, const float* __restrict__ cb,
    float* __restrict__ out, const unsigned* __restrict__ counter,
    const int* __restrict__ amb, float* __restrict__ gsumsq,
    unsigned* __restrict__ ticket, const unsigned* __restrict__ minK,
    float* __restrict__ out_loss)
{
    __shared__ __align__(16) float cbS[16384];   // 64 KB: 256 codes x 64 dims
    __shared__ double xs[64];
    __shared__ double bd[256];
    __shared__ int    bi[256];
    __shared__ unsigned lastS;
    __shared__ float redS[4];

    const int tid = threadIdx.x;

    // ---- A: fp64 re-decision for ambiguous rows (coalesced cb staging) ----
    unsigned cnt = *counter; if (cnt > AMB_CAP) cnt = AMB_CAP;
    for (unsigned i = blockIdx.x; i < cnt; i += gridDim.x) {
        int row = amb[2*i], oldk = amb[2*i+1];
        __syncthreads();
        if (tid < 64) xs[tid] = (double)x[(size_t)row*64 + tid];
        __syncthreads();
        double xn = 0.0;
        #pragma unroll 8
        for (int d = 0; d < 64; d++) xn += xs[d]*xs[d];
        double best = INFINITY; int bk = 1 << 30;
        for (int b = 0; b < 4; b++) {           // 256 codes per batch
            __syncthreads();                    // cbS free for reuse
            #pragma unroll
            for (int k = 0; k < 16; k++)        // 64 KB coalesced: 16 float4/thread
                ((float4*)cbS)[k*256 + tid] = ((const float4*)cb)[b*4096 + k*256 + tid];
            __syncthreads();
            int kcode = b*256 + tid;
            const int t6 = tid & 63;
            double dot = 0.0, cn2 = 0.0;
            #pragma unroll 8
            for (int dd = 0; dd < 64; dd++) {
                int d = (dd + t6) & 63;         // rotation: 2 lanes/bank (free)
                double cv = (double)cbS[tid*64 + d];
                dot = fma(xs[d], cv, dot);
                cn2 = fma(cv, cv, cn2);
            }
            double dist = (xn - 2.0*dot) + cn2;
            if (dist < best || (dist == best && kcode < bk)) { best = dist; bk = kcode; }
        }
        bd[tid] = best; bi[tid] = bk;
        __syncthreads();
        for (int s = 128; s > 0; s >>= 1) {
            if (tid < s) {
                double od = bd[tid+s]; int ok = bi[tid+s];
                if (od < bd[tid] || (od == bd[tid] && ok < bi[tid])) { bd[tid] = od; bi[tid] = ok; }
            }
            __syncthreads();
        }
        int bestk = bi[0];
        if (bestk != oldk) {
            double part = 0.0;
            if (tid < 64) {
                float cn = cb[(size_t)bestk*64 + tid];
                float co = cb[(size_t)oldk*64 + tid];
                out[(size_t)row*64 + tid] = cn;
                double dn = (double)cn - xs[tid];
                double dl = (double)co - xs[tid];
                part = dn*dn - dl*dl;
            }
            __syncthreads();
            bd[tid] = part;
            __syncthreads();
            for (int s = 128; s > 0; s >>= 1) {
                if (tid < s) bd[tid] += bd[tid+s];
                __syncthreads();
            }
            if (tid == 0) atomicAdd(gsumsq, (float)bd[0]);
        }
    }

    // ---- B: last block assembles the loss ----
    __syncthreads();
    if (tid == 0) {
        __threadfence();
        lastS = (atomicAdd(ticket, 1u) == 63u) ? 1u : 0u;
    }
    __syncthreads();
    if (lastS) {
        __threadfence();
        float s = 0.f;
        #pragma unroll
        for (int jj = 0; jj < 4; jj++)
            s += __uint_as_float(minK[jj*256 + tid]);   // raw bits of positive dists
        #pragma unroll
        for (int o = 32; o > 0; o >>= 1) s += __shfl_down(s, o);
        if ((tid & 63) == 0) redS[tid >> 6] = s;
        __syncthreads();
        if (tid == 0) {
            float gs = atomicAdd(gsumsq, 0.0f);         // coherent device-scope read
            float tot = redS[0] + redS[1] + redS[2] + redS[3];
            out_loss[0] = 1.25f * (gs / 2097152.0f) + 0.1f * (tot / 1024.0f);
        }
    }
}

extern "C" void kernel_launch(void* const* d_in, const int* in_sizes, int n_in,
                              void* d_out, int out_size, void* d_ws, size_t ws_size,
                              hipStream_t stream) {
    const float* x  = (const float*)d_in[0];   // [32768, 64]
    const float* cb = (const float*)d_in[1];   // [1024, 64]
    float* out = (float*)d_out;                // [0,2097152): emb; [2097152]: loss

    char* ws = (char*)d_ws;
    unsigned*       counter = (unsigned*)ws;                    // @0
    float*          gsumsq  = (float*)(ws + 4);                 // @4
    unsigned*       ticket  = (unsigned*)(ws + 8);              // @8
    float*          cn4     = (float*)(ws + 1024);              // 4 KB
    unsigned*       minK    = (unsigned*)(ws + 8192);           // 4 KB
    int*            amb     = (int*)(ws + 16384);               // 64 KB
    unsigned short* wsB     = (unsigned short*)(ws + 131072);   // 256 KB

    vq_prep<<<16,  64,  0, stream>>>(cb, cn4, minK, counter, gsumsq, ticket, wsB);
    vq_main<<<512, 512, 0, stream>>>(x, cb, wsB, cn4, out, minK, counter, amb, gsumsq);
    vq_tail<<<64,  256, 0, stream>>>(x, cb, out, counter, amb, gsumsq, ticket, minK,
                                     out + 2097152);
}